// Round 1
// 603.137 us; speedup vs baseline: 1.0678x; 1.0678x over previous
//
#include <hip/hip_runtime.h>

#define B_   32
#define H_   112
#define W_   112
#define C_   192
#define HW_  (H_*W_)      // 12544
#define BC_  (B_*C_)      // 6144
#define NPIX (B_*HW_)     // 401408
#define NROW (B_*H_)      // 3584
#define C4_  (C_/4)       // 48

__device__ __forceinline__ float sigmoidf_(float v) {
    return 1.0f / (1.0f + __expf(-v));
}

// One block per (b,h) row. SINGLE read of x; produces:
//  - per-row per-channel partial sum/max  -> psum/pmax  (deterministic, no atomics)
//  - per-pixel channel mean/max           -> avg_sp/max_sp
__global__ __launch_bounds__(256) void k_pool(const float* __restrict__ x,
                                              float* __restrict__ psum,
                                              float* __restrict__ pmax,
                                              float* __restrict__ avg_sp,
                                              float* __restrict__ max_sp) {
    const int t   = threadIdx.x;
    const int row = blockIdx.x;               // b*H_ + h
    const float4* xr = (const float4*)(x + (size_t)row * (W_ * C_)); // 112*48 float4

    const int sub = t & 15;                   // channel chunks sub, sub+16, sub+32
    const int pg  = t >> 4;                   // pixel group 0..15

    float4 s0 = {0.f,0.f,0.f,0.f}, s1 = s0, s2 = s0;
    const float NEG = -3.0e38f;
    float4 m0 = {NEG,NEG,NEG,NEG}, m1 = m0, m2 = m0;

    #pragma unroll
    for (int k = 0; k < 7; ++k) {
        const int p = pg + 16 * k;            // 16*7 == 112, exact
        float4 a = xr[p * C4_ + sub];
        float4 c = xr[p * C4_ + sub + 16];
        float4 d = xr[p * C4_ + sub + 32];

        // per-channel accumulation (reuse same registers)
        s0.x += a.x; s0.y += a.y; s0.z += a.z; s0.w += a.w;
        s1.x += c.x; s1.y += c.y; s1.z += c.z; s1.w += c.w;
        s2.x += d.x; s2.y += d.y; s2.z += d.z; s2.w += d.w;
        m0.x = fmaxf(m0.x, a.x); m0.y = fmaxf(m0.y, a.y);
        m0.z = fmaxf(m0.z, a.z); m0.w = fmaxf(m0.w, a.w);
        m1.x = fmaxf(m1.x, c.x); m1.y = fmaxf(m1.y, c.y);
        m1.z = fmaxf(m1.z, c.z); m1.w = fmaxf(m1.w, c.w);
        m2.x = fmaxf(m2.x, d.x); m2.y = fmaxf(m2.y, d.y);
        m2.z = fmaxf(m2.z, d.z); m2.w = fmaxf(m2.w, d.w);

        // per-pixel channel reduction across the 16 sub-lanes
        float s = (a.x + a.y + a.z + a.w) + (c.x + c.y + c.z + c.w) + (d.x + d.y + d.z + d.w);
        float m = fmaxf(fmaxf(fmaxf(a.x, a.y), fmaxf(a.z, a.w)),
                 fmaxf(fmaxf(fmaxf(c.x, c.y), fmaxf(c.z, c.w)),
                       fmaxf(fmaxf(fmaxf(d.x, d.y), fmaxf(d.z, d.w)), NEG)));
        #pragma unroll
        for (int sh = 1; sh < 16; sh <<= 1) {
            s += __shfl_xor(s, sh, 64);
            m = fmaxf(m, __shfl_xor(m, sh, 64));
        }
        if (sub == 0) {
            avg_sp[row * W_ + p] = s * (1.0f / C_);
            max_sp[row * W_ + p] = m;
        }
    }

    // cross-pixel-group reduce of per-channel partials (LDS), then one clean store
    __shared__ float4 lsum[16][49];   // [pg][chunk], padded stride 49 (bank-friendly)
    __shared__ float4 lmax[16][49];
    lsum[pg][sub]      = s0; lsum[pg][sub + 16] = s1; lsum[pg][sub + 32] = s2;
    lmax[pg][sub]      = m0; lmax[pg][sub + 16] = m1; lmax[pg][sub + 32] = m2;
    __syncthreads();
    if (t < C4_) {
        float4 S = lsum[0][t], M = lmax[0][t];
        #pragma unroll
        for (int g = 1; g < 16; ++g) {
            float4 o  = lsum[g][t];
            S.x += o.x; S.y += o.y; S.z += o.z; S.w += o.w;
            float4 om = lmax[g][t];
            M.x = fmaxf(M.x, om.x); M.y = fmaxf(M.y, om.y);
            M.z = fmaxf(M.z, om.z); M.w = fmaxf(M.w, om.w);
        }
        ((float4*)psum)[row * C4_ + t] = S;
        ((float4*)pmax)[row * C4_ + t] = M;
    }
}

// Reduce 112 row-partials per (b,c), then SE + CBAM channel MLPs.
// scale[b,c] = sigmoid(SE) * sigmoid(mlp(avg)+mlp(max))
__global__ __launch_bounds__(192) void k_small(const float* __restrict__ psum,
                                               const float* __restrict__ pmax,
                                               const float* __restrict__ se_w1,
                                               const float* __restrict__ se_b1,
                                               const float* __restrict__ se_w2,
                                               const float* __restrict__ se_b2,
                                               const float* __restrict__ mlp_w1,
                                               const float* __restrict__ mlp_b1,
                                               const float* __restrict__ mlp_w2,
                                               const float* __restrict__ mlp_b2,
                                               float* __restrict__ scale) {
    const int b = blockIdx.x, t = threadIdx.x;
    const float* ps = psum + (size_t)b * H_ * C_ + t;
    const float* pm = pmax + (size_t)b * H_ * C_ + t;
    float s = 0.f, m = -3.0e38f;
    #pragma unroll 4
    for (int h = 0; h < H_; ++h) {          // coalesced: threads span c
        s += ps[h * C_];
        m = fmaxf(m, pm[h * C_]);
    }
    __shared__ float avg[C_], mx[C_], hse[12], ha[24], hm[24];
    avg[t] = s * (1.0f / HW_);
    mx[t]  = m;
    __syncthreads();
    if (t < 12) {
        float z = se_b1[t];
        for (int c = 0; c < C_; ++c) z += avg[c] * se_w1[c * 12 + t];
        hse[t] = z * sigmoidf_(z);          // swish
    }
    if (t < 24) {
        float za = mlp_b1[t], zm = mlp_b1[t];
        for (int c = 0; c < C_; ++c) {
            float w = mlp_w1[c * 24 + t];
            za += avg[c] * w;
            zm += mx[c] * w;
        }
        ha[t] = za * sigmoidf_(za);
        hm[t] = zm * sigmoidf_(zm);
    }
    __syncthreads();
    float sv = se_b2[t];
    #pragma unroll
    for (int j = 0; j < 12; ++j) sv += hse[j] * se_w2[j * C_ + t];
    float av = 2.0f * mlp_b2[t];            // mlp(avg)+mlp(max): bias twice
    #pragma unroll
    for (int j = 0; j < 24; ++j) av += (ha[j] + hm[j]) * mlp_w2[j * C_ + t];
    scale[b * C_ + t] = sigmoidf_(sv) * sigmoidf_(av);
}

// Fused: 7x7 SAME conv (per-row, LDS-tiled, branch-free taps) + sigmoid + apply.
// One block per (b,y) row; out = x * scale[b,c] * satt[b,y,x]
__global__ __launch_bounds__(256) void k_apply(const float4* __restrict__ x4,
                                               const float* __restrict__ scale,
                                               const float* __restrict__ avg_sp,
                                               const float* __restrict__ max_sp,
                                               const float* __restrict__ conv_k,
                                               const float* __restrict__ conv_b,
                                               float4* __restrict__ out4) {
    const int t   = threadIdx.x;
    const int row = blockIdx.x;             // b*H_ + y
    const int b   = row / H_;
    const int y   = row - b * H_;

    __shared__ float sA[7][118];            // x in [-3, 114], zero-padded
    __shared__ float sM[7][118];
    __shared__ float ssc[C_];
    __shared__ float patt[2][112];
    __shared__ float ssatt[112];

    if (t < C_) ssc[t] = scale[b * C_ + t];

    const float* ab = avg_sp + (size_t)b * HW_;
    const float* mb = max_sp + (size_t)b * HW_;
    for (int i = t; i < 7 * 118; i += 256) {
        const int r  = i / 118;
        const int cc = i - r * 118;
        const int yy = y + r - 3;
        const int xx = cc - 3;
        float va = 0.f, vm = 0.f;
        if (yy >= 0 && yy < H_ && xx >= 0 && xx < W_) {
            va = ab[yy * W_ + xx];
            vm = mb[yy * W_ + xx];
        }
        sA[r][cc] = va;
        sM[r][cc] = vm;
    }
    __syncthreads();

    // conv split over two wave-pairs: half 0 -> dy 0..3, half 1 -> dy 4..6
    const int half = t >> 7;                // wave-uniform
    const int px   = t & 127;
    if (px < 112) {
        float acc = 0.f;
        if (half == 0) {
            #pragma unroll
            for (int dy = 0; dy < 4; ++dy)
                #pragma unroll
                for (int dx = 0; dx < 7; ++dx)
                    acc += sA[dy][px + dx] * conv_k[(dy * 7 + dx) * 2]
                         + sM[dy][px + dx] * conv_k[(dy * 7 + dx) * 2 + 1];
        } else {
            #pragma unroll
            for (int dy = 4; dy < 7; ++dy)
                #pragma unroll
                for (int dx = 0; dx < 7; ++dx)
                    acc += sA[dy][px + dx] * conv_k[(dy * 7 + dx) * 2]
                         + sM[dy][px + dx] * conv_k[(dy * 7 + dx) * 2 + 1];
        }
        patt[half][px] = acc;
    }
    __syncthreads();
    if (t < 112) ssatt[t] = sigmoidf_(patt[0][t] + patt[1][t] + conv_b[0]);
    __syncthreads();

    // apply sweep: 112 pixels * 48 float4 = 5376 = 21 * 256
    const float4* xrow = x4   + (size_t)row * (W_ * C4_);
    float4*       orow = out4 + (size_t)row * (W_ * C4_);
    #pragma unroll
    for (int i = 0; i < 21; ++i) {
        const int idx = i * 256 + t;
        const int pl  = idx / C4_;
        const int c4  = idx - pl * C4_;
        const float  ss = ssatt[pl];
        const float4 sc = ((const float4*)ssc)[c4];
        float4 v = xrow[idx];
        float4 o;
        o.x = v.x * sc.x * ss;
        o.y = v.y * sc.y * ss;
        o.z = v.z * sc.z * ss;
        o.w = v.w * sc.w * ss;
        orow[idx] = o;
    }
}

extern "C" void kernel_launch(void* const* d_in, const int* in_sizes, int n_in,
                              void* d_out, int out_size, void* d_ws, size_t ws_size,
                              hipStream_t stream) {
    (void)in_sizes; (void)n_in; (void)out_size; (void)ws_size;
    const float* x      = (const float*)d_in[0];
    const float* se_w1  = (const float*)d_in[1];
    const float* se_b1  = (const float*)d_in[2];
    const float* se_w2  = (const float*)d_in[3];
    const float* se_b2  = (const float*)d_in[4];
    const float* mlp_w1 = (const float*)d_in[5];
    const float* mlp_b1 = (const float*)d_in[6];
    const float* mlp_w2 = (const float*)d_in[7];
    const float* mlp_b2 = (const float*)d_in[8];
    const float* conv_k = (const float*)d_in[9];
    const float* conv_b = (const float*)d_in[10];
    float* out = (float*)d_out;

    float* ws     = (float*)d_ws;
    float* psum   = ws;                         // NROW*C_ = 688128 floats
    float* pmax   = ws + 688128;                // 688128 floats
    float* scale  = ws + 1376256;               // 6144 floats
    float* avg_sp = ws + 1382400;               // 401408 floats
    float* max_sp = ws + 1783808;               // 401408 floats

    k_pool <<<NROW, 256, 0, stream>>>(x, psum, pmax, avg_sp, max_sp);
    k_small<<<B_, 192, 0, stream>>>(psum, pmax, se_w1, se_b1, se_w2, se_b2,
                                    mlp_w1, mlp_b1, mlp_w2, mlp_b2, scale);
    k_apply<<<NROW, 256, 0, stream>>>((const float4*)x, scale, avg_sp, max_sp,
                                      conv_k, conv_b, (float4*)out);
}

// Round 2
// 599.145 us; speedup vs baseline: 1.0749x; 1.0067x over previous
//
#include <hip/hip_runtime.h>

#define B_   32
#define H_   112
#define W_   112
#define C_   192
#define HW_  (H_*W_)      // 12544
#define NROW (B_*H_)      // 3584
#define C4_  (C_/4)       // 48

__device__ __forceinline__ float sigmoidf_(float v) {
    return 1.0f / (1.0f + __expf(-v));
}

// One block per (b,h) row. SINGLE read of x; produces:
//  - per-row per-channel partial sum/max  -> psum/pmax  (deterministic, no atomics)
//  - per-pixel channel mean/max           -> avg_sp/max_sp
// LDS arena is reused (phase1: per-pixel staging; phase2: per-channel reduce).
__global__ __launch_bounds__(256) void k_pool(const float* __restrict__ x,
                                              float* __restrict__ psum,
                                              float* __restrict__ pmax,
                                              float* __restrict__ avg_sp,
                                              float* __restrict__ max_sp) {
    const int t   = threadIdx.x;
    const int row = blockIdx.x;               // b*H_ + h
    const float4* xr = (const float4*)(x + (size_t)row * (W_ * C_)); // 112*48 float4

    const int sub = t & 15;                   // channel chunks sub, sub+16, sub+32
    const int pg  = t >> 4;                   // pixel group 0..15

    // 25088-byte arena, aliased across phases (keeps occupancy at 6 blocks/CU)
    __shared__ __align__(16) unsigned char arena[25088];
    float  (*lps)[20] = (float  (*)[20])(arena);           // [112][20] padded
    float  (*lpm)[20] = (float  (*)[20])(arena + 8960);    // [112][20] padded
    float4 *lsum      = (float4*)(arena);                  // [16][49] flattened
    float4 *lmax      = (float4*)(arena + 12544);          // [16][49] flattened

    float4 s0 = {0.f,0.f,0.f,0.f}, s1 = s0, s2 = s0;
    const float NEG = -3.0e38f;
    float4 m0 = {NEG,NEG,NEG,NEG}, m1 = m0, m2 = m0;

    #pragma unroll
    for (int k = 0; k < 7; ++k) {
        const int p = pg + 16 * k;            // 16*7 == 112, exact
        float4 a = xr[p * C4_ + sub];
        float4 c = xr[p * C4_ + sub + 16];
        float4 d = xr[p * C4_ + sub + 32];

        // per-channel accumulation (registers)
        s0.x += a.x; s0.y += a.y; s0.z += a.z; s0.w += a.w;
        s1.x += c.x; s1.y += c.y; s1.z += c.z; s1.w += c.w;
        s2.x += d.x; s2.y += d.y; s2.z += d.z; s2.w += d.w;
        m0.x = fmaxf(m0.x, a.x); m0.y = fmaxf(m0.y, a.y);
        m0.z = fmaxf(m0.z, a.z); m0.w = fmaxf(m0.w, a.w);
        m1.x = fmaxf(m1.x, c.x); m1.y = fmaxf(m1.y, c.y);
        m1.z = fmaxf(m1.z, c.z); m1.w = fmaxf(m1.w, c.w);
        m2.x = fmaxf(m2.x, d.x); m2.y = fmaxf(m2.y, d.y);
        m2.z = fmaxf(m2.z, d.z); m2.w = fmaxf(m2.w, d.w);

        // per-pixel 12-channel partial -> LDS (2 ds_write_b32, no shuffles)
        float s = (a.x + a.y + a.z + a.w) + (c.x + c.y + c.z + c.w) + (d.x + d.y + d.z + d.w);
        float m = fmaxf(fmaxf(fmaxf(a.x, a.y), fmaxf(a.z, a.w)),
                 fmaxf(fmaxf(fmaxf(c.x, c.y), fmaxf(c.z, c.w)),
                       fmaxf(fmaxf(d.x, d.y), fmaxf(d.z, d.w))));
        lps[p][sub] = s;
        lpm[p][sub] = m;
    }
    __syncthreads();

    // per-pixel final reduce: 112 threads, 8x ds_read_b128, coalesced global store
    if (t < W_) {
        const float4* ra = (const float4*)lps[t];   // stride 80B -> 16B aligned
        const float4* rm = (const float4*)lpm[t];
        float4 A0 = ra[0], A1 = ra[1], A2 = ra[2], A3 = ra[3];
        float s = (A0.x + A0.y + A0.z + A0.w) + (A1.x + A1.y + A1.z + A1.w)
                + (A2.x + A2.y + A2.z + A2.w) + (A3.x + A3.y + A3.z + A3.w);
        float4 M0 = rm[0], M1 = rm[1], M2 = rm[2], M3 = rm[3];
        float m = fmaxf(fmaxf(fmaxf(fmaxf(M0.x, M0.y), fmaxf(M0.z, M0.w)),
                              fmaxf(fmaxf(M1.x, M1.y), fmaxf(M1.z, M1.w))),
                        fmaxf(fmaxf(fmaxf(M2.x, M2.y), fmaxf(M2.z, M2.w)),
                              fmaxf(fmaxf(M3.x, M3.y), fmaxf(M3.z, M3.w))));
        avg_sp[row * W_ + t] = s * (1.0f / C_);
        max_sp[row * W_ + t] = m;
    }
    __syncthreads();   // all lps/lpm reads done before arena is reused

    // cross-pixel-group reduce of per-channel partials, then one clean store
    lsum[pg * 49 + sub]      = s0; lsum[pg * 49 + sub + 16] = s1; lsum[pg * 49 + sub + 32] = s2;
    lmax[pg * 49 + sub]      = m0; lmax[pg * 49 + sub + 16] = m1; lmax[pg * 49 + sub + 32] = m2;
    __syncthreads();
    if (t < C4_) {
        float4 S = lsum[t], M = lmax[t];
        #pragma unroll
        for (int g = 1; g < 16; ++g) {
            float4 o  = lsum[g * 49 + t];
            S.x += o.x; S.y += o.y; S.z += o.z; S.w += o.w;
            float4 om = lmax[g * 49 + t];
            M.x = fmaxf(M.x, om.x); M.y = fmaxf(M.y, om.y);
            M.z = fmaxf(M.z, om.z); M.w = fmaxf(M.w, om.w);
        }
        ((float4*)psum)[row * C4_ + t] = S;
        ((float4*)pmax)[row * C4_ + t] = M;
    }
}

// Reduce 112 row-partials per (b,c), then SE + CBAM channel MLPs.
// scale[b,c] = sigmoid(SE) * sigmoid(mlp(avg)+mlp(max))
__global__ __launch_bounds__(192) void k_small(const float* __restrict__ psum,
                                               const float* __restrict__ pmax,
                                               const float* __restrict__ se_w1,
                                               const float* __restrict__ se_b1,
                                               const float* __restrict__ se_w2,
                                               const float* __restrict__ se_b2,
                                               const float* __restrict__ mlp_w1,
                                               const float* __restrict__ mlp_b1,
                                               const float* __restrict__ mlp_w2,
                                               const float* __restrict__ mlp_b2,
                                               float* __restrict__ scale) {
    const int b = blockIdx.x, t = threadIdx.x;
    const float* ps = psum + (size_t)b * H_ * C_ + t;
    const float* pm = pmax + (size_t)b * H_ * C_ + t;
    float s = 0.f, m = -3.0e38f;
    #pragma unroll 8
    for (int h = 0; h < H_; ++h) {          // coalesced: threads span c
        s += ps[h * C_];
        m = fmaxf(m, pm[h * C_]);
    }
    __shared__ float avg[C_], mx[C_], hse[12], ha[24], hm[24];
    avg[t] = s * (1.0f / HW_);
    mx[t]  = m;
    __syncthreads();
    if (t < 12) {
        float z = se_b1[t];
        for (int c = 0; c < C_; ++c) z += avg[c] * se_w1[c * 12 + t];
        hse[t] = z * sigmoidf_(z);          // swish
    }
    if (t < 24) {
        float za = mlp_b1[t], zm = mlp_b1[t];
        for (int c = 0; c < C_; ++c) {
            float w = mlp_w1[c * 24 + t];
            za += avg[c] * w;
            zm += mx[c] * w;
        }
        ha[t] = za * sigmoidf_(za);
        hm[t] = zm * sigmoidf_(zm);
    }
    __syncthreads();
    float sv = se_b2[t];
    #pragma unroll
    for (int j = 0; j < 12; ++j) sv += hse[j] * se_w2[j * C_ + t];
    float av = 2.0f * mlp_b2[t];            // mlp(avg)+mlp(max): bias twice
    #pragma unroll
    for (int j = 0; j < 24; ++j) av += (ha[j] + hm[j]) * mlp_w2[j * C_ + t];
    scale[b * C_ + t] = sigmoidf_(sv) * sigmoidf_(av);
}

// Fused: 7x7 SAME conv (per-row, LDS-tiled, branch-free taps) + sigmoid + apply.
// One block per (b,y) row; out = x * scale[b,c] * satt[b,y,x]
__global__ __launch_bounds__(256) void k_apply(const float4* __restrict__ x4,
                                               const float* __restrict__ scale,
                                               const float* __restrict__ avg_sp,
                                               const float* __restrict__ max_sp,
                                               const float* __restrict__ conv_k,
                                               const float* __restrict__ conv_b,
                                               float4* __restrict__ out4) {
    const int t   = threadIdx.x;
    const int row = blockIdx.x;             // b*H_ + y
    const int b   = row / H_;
    const int y   = row - b * H_;

    __shared__ float sA[7][118];            // x in [-3, 114], zero-padded
    __shared__ float sM[7][118];
    __shared__ __align__(16) float ssc[C_];
    __shared__ float patt[2][112];
    __shared__ float ssatt[112];

    if (t < C4_) ((float4*)ssc)[t] = ((const float4*)(scale + b * C_))[t];

    const float* ab = avg_sp + (size_t)b * HW_;
    const float* mb = max_sp + (size_t)b * HW_;
    for (int i = t; i < 7 * 118; i += 256) {
        const int r  = i / 118;
        const int cc = i - r * 118;
        const int yy = y + r - 3;
        const int xx = cc - 3;
        float va = 0.f, vm = 0.f;
        if (yy >= 0 && yy < H_ && xx >= 0 && xx < W_) {
            va = ab[yy * W_ + xx];
            vm = mb[yy * W_ + xx];
        }
        sA[r][cc] = va;
        sM[r][cc] = vm;
    }
    __syncthreads();

    // conv split over two wave-pairs: half 0 -> dy 0..3, half 1 -> dy 4..6
    const int half = t >> 7;                // wave-uniform
    const int px   = t & 127;
    if (px < 112) {
        float acc = 0.f;
        if (half == 0) {
            #pragma unroll
            for (int dy = 0; dy < 4; ++dy)
                #pragma unroll
                for (int dx = 0; dx < 7; ++dx)
                    acc += sA[dy][px + dx] * conv_k[(dy * 7 + dx) * 2]
                         + sM[dy][px + dx] * conv_k[(dy * 7 + dx) * 2 + 1];
        } else {
            #pragma unroll
            for (int dy = 4; dy < 7; ++dy)
                #pragma unroll
                for (int dx = 0; dx < 7; ++dx)
                    acc += sA[dy][px + dx] * conv_k[(dy * 7 + dx) * 2]
                         + sM[dy][px + dx] * conv_k[(dy * 7 + dx) * 2 + 1];
        }
        patt[half][px] = acc;
    }
    __syncthreads();
    if (t < 112) ssatt[t] = sigmoidf_(patt[0][t] + patt[1][t] + conv_b[0]);
    __syncthreads();

    // apply sweep: 112 pixels * 48 float4 = 5376 = 21 * 256
    const float4* xrow = x4   + (size_t)row * (W_ * C4_);
    float4*       orow = out4 + (size_t)row * (W_ * C4_);
    #pragma unroll
    for (int i = 0; i < 21; ++i) {
        const int idx = i * 256 + t;
        const int pl  = idx / C4_;
        const int c4  = idx - pl * C4_;
        const float  ss = ssatt[pl];
        const float4 sc = ((const float4*)ssc)[c4];
        float4 v = xrow[idx];
        float4 o;
        o.x = v.x * sc.x * ss;
        o.y = v.y * sc.y * ss;
        o.z = v.z * sc.z * ss;
        o.w = v.w * sc.w * ss;
        orow[idx] = o;
    }
}

extern "C" void kernel_launch(void* const* d_in, const int* in_sizes, int n_in,
                              void* d_out, int out_size, void* d_ws, size_t ws_size,
                              hipStream_t stream) {
    (void)in_sizes; (void)n_in; (void)out_size; (void)ws_size;
    const float* x      = (const float*)d_in[0];
    const float* se_w1  = (const float*)d_in[1];
    const float* se_b1  = (const float*)d_in[2];
    const float* se_w2  = (const float*)d_in[3];
    const float* se_b2  = (const float*)d_in[4];
    const float* mlp_w1 = (const float*)d_in[5];
    const float* mlp_b1 = (const float*)d_in[6];
    const float* mlp_w2 = (const float*)d_in[7];
    const float* mlp_b2 = (const float*)d_in[8];
    const float* conv_k = (const float*)d_in[9];
    const float* conv_b = (const float*)d_in[10];
    float* out = (float*)d_out;

    float* ws     = (float*)d_ws;
    float* psum   = ws;                         // NROW*C_ = 688128 floats
    float* pmax   = ws + 688128;                // 688128 floats
    float* scale  = ws + 1376256;               // 6144 floats
    float* avg_sp = ws + 1382400;               // 401408 floats
    float* max_sp = ws + 1783808;               // 401408 floats

    k_pool <<<NROW, 256, 0, stream>>>(x, psum, pmax, avg_sp, max_sp);
    k_small<<<B_, 192, 0, stream>>>(psum, pmax, se_w1, se_b1, se_w2, se_b2,
                                    mlp_w1, mlp_b1, mlp_w2, mlp_b2, scale);
    k_apply<<<NROW, 256, 0, stream>>>((const float4*)x, scale, avg_sp, max_sp,
                                      conv_k, conv_b, (float4*)out);
}